// Round 7
// baseline (327.210 us; speedup 1.0000x reference)
//
#include <hip/hip_runtime.h>

// ---------------------------------------------------------------------------
// BidirectionalAttention: B=2, S=4096, D=768, H=6, KVH=2, HD=128 (GQA x3)
// bf16 MFMA everywhere, fp32 accum.
// R7: k_attn 4-wave blocks (128 q-rows, K/V shared by 4 waves) -> 2 waves/SIMD
//     at 80KB LDS x 2 blocks/CU. V-transpose folded into QKV-GEMM epilogue
//     (packed 8B transposed stores); k_vtrans deleted. vT aliases ob region.
// ---------------------------------------------------------------------------

typedef __attribute__((ext_vector_type(8))) short bf16x8;   // 8 bf16 = 4 VGPRs
typedef __attribute__((ext_vector_type(4))) float floatx4;
typedef __attribute__((ext_vector_type(4))) unsigned short ushort4v;

#define MFMA16(a, b, c) __builtin_amdgcn_mfma_f32_16x16x32_bf16((a), (b), (c), 0, 0, 0)

#if __has_builtin(__builtin_amdgcn_exp2f)
#define EXP2F(x) __builtin_amdgcn_exp2f(x)
#else
#define EXP2F(x) exp2f(x)
#endif

#define GLOAD_LDS16(gptr, lptr)                                                   \
  __builtin_amdgcn_global_load_lds(                                               \
      (const __attribute__((address_space(1))) unsigned int*)(gptr),              \
      (__attribute__((address_space(3))) unsigned int*)(lptr), 16, 0, 0)

__device__ __forceinline__ unsigned short f2bf(float f) {   // RNE
  unsigned int u = __builtin_bit_cast(unsigned int, f);
  u = u + 0x7FFFu + ((u >> 16) & 1u);
  return (unsigned short)(u >> 16);
}

__device__ __forceinline__ unsigned short f2bf_fast(float f) {  // round-half-up
  unsigned int u = __builtin_bit_cast(unsigned int, f);
  return (unsigned short)((u + 0x8000u) >> 16);
}

__device__ __forceinline__ float bf2f(unsigned short v) {
  return __builtin_bit_cast(float, (unsigned int)v << 16);
}

// ---------------- convert kernels ----------------

__global__ __launch_bounds__(256) void k_cvt_x(const float* __restrict__ x,
                                               unsigned short* __restrict__ xb, int n) {
  int i = (blockIdx.x * 256 + threadIdx.x) * 4;
  if (i + 3 < n) {
    float4 v = *(const float4*)(x + i);
    xb[i + 0] = f2bf(v.x);
    xb[i + 1] = f2bf(v.y);
    xb[i + 2] = f2bf(v.z);
    xb[i + 3] = f2bf(v.w);
  }
}

__global__ __launch_bounds__(256) void k_cvt_wqkv(const float* __restrict__ wq,
                                                  const float* __restrict__ wk,
                                                  const float* __restrict__ wv,
                                                  unsigned short* __restrict__ wt) {
  const float QSCALE = 1.4426950408889634f * 0.08838834764831843f; // log2(e)/sqrt(128)
  int idx = blockIdx.x * 256 + threadIdx.x;       // < 1280*768
  int n = idx / 768, k = idx - n * 768;
  float v;
  if (n < 768)       v = wq[k * 768 + n] * QSCALE;
  else if (n < 1024) v = wk[k * 256 + (n - 768)];
  else               v = wv[k * 256 + (n - 1024)];
  wt[idx] = f2bf(v);
}

__global__ __launch_bounds__(256) void k_cvt_wo(const float* __restrict__ wo,
                                                unsigned short* __restrict__ wt) {
  int idx = blockIdx.x * 256 + threadIdx.x;       // < 768*768
  int n = idx / 768, k = idx - n * 768;
  wt[idx] = f2bf(wo[k * 768 + n]);
}

// ---------------- GEMM: C[M,N] = A[M,K] @ Bt[N,K]^T ----------------
// SPLIT_V: columns >=1024 (the V projection) are written TRANSPOSED to
// vTout[(b,kvh,d)][s] as packed 8B stores instead of to C.

__device__ __forceinline__ void store_out(float* C, int i, float v) { C[i] = v; }
__device__ __forceinline__ void store_out(unsigned short* C, int i, float v) { C[i] = f2bf(v); }

template <typename OUT_T, bool SPLIT_V>
__global__ __launch_bounds__(256) void k_gemm(const unsigned short* __restrict__ A, int lda,
                                              const unsigned short* __restrict__ Bt, int ldb,
                                              OUT_T* __restrict__ C, int ldc, int K,
                                              unsigned short* __restrict__ vTout) {
  __shared__ __align__(16) unsigned short As[128 * 40];
  __shared__ __align__(16) unsigned short Bs[128 * 40];
  const int tid = threadIdx.x;
  const int wave = tid >> 6, lane = tid & 63;
  const int quad = lane >> 4, l16 = lane & 15;
  const int wm = (wave >> 1) * 64, wn = (wave & 1) * 64;
  const int m0 = blockIdx.y * 128, n0 = blockIdx.x * 128;

  floatx4 acc[4][4] = {};
  const int srow = tid >> 2;
  const int sseg = (tid & 3) * 8;

  for (int k0 = 0; k0 < K; k0 += 32) {
    __syncthreads();
#pragma unroll
    for (int h = 0; h < 2; h++) {
      int r = srow + h * 64;
      *(uint4*)(&As[r * 40 + sseg]) = *(const uint4*)(&A[(m0 + r) * lda + k0 + sseg]);
      *(uint4*)(&Bs[r * 40 + sseg]) = *(const uint4*)(&Bt[(n0 + r) * ldb + k0 + sseg]);
    }
    __syncthreads();

    bf16x8 af[4], bfr[4];
#pragma unroll
    for (int mf = 0; mf < 4; mf++)
      af[mf] = *(const bf16x8*)(&As[(wm + mf * 16 + l16) * 40 + quad * 8]);
#pragma unroll
    for (int nf = 0; nf < 4; nf++)
      bfr[nf] = *(const bf16x8*)(&Bs[(wn + nf * 16 + l16) * 40 + quad * 8]);
#pragma unroll
    for (int mf = 0; mf < 4; mf++)
#pragma unroll
      for (int nf = 0; nf < 4; nf++)
        acc[mf][nf] = MFMA16(af[mf], bfr[nf], acc[mf][nf]);
  }

#pragma unroll
  for (int mf = 0; mf < 4; mf++)
#pragma unroll
    for (int nf = 0; nf < 4; nf++) {
      int col = n0 + wn + nf * 16 + l16;
      if (SPLIT_V && col >= 1024) {
        // transposed V store: vT[(b,kvh,d)][s], 4 consecutive s per lane
        int cc = col - 1024;
        int kvhh = cc >> 7, d = cc & 127;
        int row0 = m0 + wm + mf * 16 + quad * 4;
        int bb = row0 >> 12, s = row0 & 4095;
        ushort4v pv;
        pv.x = f2bf(acc[mf][nf][0]);
        pv.y = f2bf(acc[mf][nf][1]);
        pv.z = f2bf(acc[mf][nf][2]);
        pv.w = f2bf(acc[mf][nf][3]);
        *(ushort4v*)(&vTout[((size_t)((bb * 2 + kvhh) * 128) + d) * 4096 + s]) = pv;
      } else {
#pragma unroll
        for (int r = 0; r < 4; r++) {
          int row = m0 + wm + mf * 16 + quad * 4 + r;
          store_out(C, row * ldc + col, acc[mf][nf][r]);
        }
      }
    }
}

// ---------------- flash attention (segmented, double-buffered, 4 waves) -------
// grid (S/128, H, B*NSEG): z = seg*2 + b. 16 kt-iters per block, unnormalized
// O-partial (bf16) + l-partial (fp32). 256 thr = 4 waves; wave owns 32 q.
// Swizzled LDS (16B chunk c stored at c ^ (r&7)).

#define NSEG 4

#define KS_OFF(row, c) (((row) << 7) + ((((c) ^ ((row) & 7))) << 3))
#define VS_OFF(row, c) (((row) << 6) + ((((c) ^ ((row) & 7))) << 3))

__global__ __launch_bounds__(256) void k_attn(const unsigned short* __restrict__ qkv,
                                              const unsigned short* __restrict__ vT,
                                              unsigned short* __restrict__ Opart,
                                              float* __restrict__ lpart) {
  __shared__ __align__(16) unsigned short Ks0[64 * 128];   // 16 KB
  __shared__ __align__(16) unsigned short Ks1[64 * 128];   // 16 KB
  __shared__ __align__(16) unsigned short Vt0[128 * 64];   // 16 KB
  __shared__ __align__(16) unsigned short Vt1[128 * 64];   // 16 KB
  __shared__ __align__(16) unsigned short Ps[128 * 64];    // 16 KB

  const int qt = blockIdx.x, h = blockIdx.y;
  const int seg = blockIdx.z >> 1, b = blockIdx.z & 1;
  const int kvh = h / 3;
  const int tid = threadIdx.x, w = tid >> 6, lane = tid & 63;
  const int quad = lane >> 4, l16 = lane & 15;

  const char* qbase = (const char*)(qkv + (size_t)(b * 4096) * 1280 + h * 128);
  const char* kbase = (const char*)(qkv + (size_t)(b * 4096) * 1280 + 768 + kvh * 128);
  const char* vtb   = (const char*)(vT + (size_t)((b * 2 + kvh) * 128) * 4096);

  bf16x8 qf[2][4];
  floatx4 acc[2][8] = {};
  float l_i[2] = {0.f, 0.f};

  // ---- stage Q tile (128x128) into Ks0 (rows 0-63) + Ks1 (rows 64-127) ----
#pragma unroll
  for (int it = 0; it < 8; it++) {
    int cb = it * 256 + w * 64;              // wave-uniform chunk base
    int j = cb + lane;
    int r = j >> 4, c = (j & 15) ^ (r & 7);
    unsigned short* dst = (cb < 1024) ? &Ks0[cb * 8] : &Ks1[(cb - 1024) * 8];
    GLOAD_LDS16(qbase + (size_t)(qt * 128 + r) * 2560 + c * 16, dst);
  }
  __syncthreads();

  // wave w owns q-rows w*32..w*32+31; rows 0-63 in Ks0, 64-127 in Ks1
  {
    const unsigned short* qsrc = (w < 2) ? Ks0 : Ks1;
    const int qr0 = (w & 1) * 32;
#pragma unroll
    for (int qg = 0; qg < 2; qg++)
#pragma unroll
      for (int dc = 0; dc < 4; dc++)
        qf[qg][dc] = *(const bf16x8*)(&qsrc[KS_OFF(qr0 + qg * 16 + l16, dc * 4 + quad)]);
  }
  __syncthreads();   // all waves done reading Q before K/V overwrite

  auto stage_kv = [&](int kt, unsigned short* KsB, unsigned short* VtB) {
#pragma unroll
    for (int it = 0; it < 4; it++) {
      int cb = it * 256 + w * 64;
      int j = cb + lane;
      int r = j >> 4, c = (j & 15) ^ (r & 7);
      GLOAD_LDS16(kbase + (size_t)(kt * 64 + r) * 2560 + c * 16, &KsB[cb * 8]);
    }
#pragma unroll
    for (int it = 0; it < 4; it++) {
      int cb = it * 256 + w * 64;
      int j = cb + lane;
      int r = j >> 3, c = (j & 7) ^ (r & 7);
      GLOAD_LDS16(vtb + (size_t)r * 8192 + kt * 128 + c * 16, &VtB[cb * 8]);
    }
  };

  auto compute_tile = [&](const unsigned short* KsB, const unsigned short* VtB) {
    // S^T = K Q^T : D[m=kcol][n=q]; kf reused across both q-groups
    floatx4 sfr[2][4] = {};
#pragma unroll
    for (int nf = 0; nf < 4; nf++)
#pragma unroll
      for (int dc = 0; dc < 4; dc++) {
        bf16x8 kf = *(const bf16x8*)(&KsB[KS_OFF(nf * 16 + l16, dc * 4 + quad)]);
        sfr[0][nf] = MFMA16(kf, qf[0][dc], sfr[0][nf]);
        sfr[1][nf] = MFMA16(kf, qf[1][dc], sfr[1][nf]);
      }

    // no-max softmax; P -> wave-private swizzled LDS rows (b64 packed)
#pragma unroll
    for (int qg = 0; qg < 2; qg++) {
      float rs = 0.f;
#pragma unroll
      for (int nf = 0; nf < 4; nf++) {
#pragma unroll
        for (int r = 0; r < 4; r++) {
          float p = EXP2F(sfr[qg][nf][r]);
          sfr[qg][nf][r] = p;
          rs += p;
        }
        int row = w * 32 + qg * 16 + l16;
        int ch = nf * 2 + (quad >> 1);
        ushort4v pw;
        pw.x = f2bf_fast(sfr[qg][nf][0]);
        pw.y = f2bf_fast(sfr[qg][nf][1]);
        pw.z = f2bf_fast(sfr[qg][nf][2]);
        pw.w = f2bf_fast(sfr[qg][nf][3]);
        *(ushort4v*)(&Ps[VS_OFF(row, ch) + (quad & 1) * 4]) = pw;
      }
      rs += __shfl_xor(rs, 16, 64);
      rs += __shfl_xor(rs, 32, 64);
      l_i[qg] += rs;
    }

    // O += P V : vf reused across both q-groups (wave-private P: DS in-order)
#pragma unroll
    for (int kc = 0; kc < 2; kc++) {
      bf16x8 pf0 = *(const bf16x8*)(&Ps[VS_OFF(w * 32 + l16, kc * 4 + quad)]);
      bf16x8 pf1 = *(const bf16x8*)(&Ps[VS_OFF(w * 32 + 16 + l16, kc * 4 + quad)]);
#pragma unroll
      for (int df = 0; df < 8; df++) {
        bf16x8 vf = *(const bf16x8*)(&VtB[VS_OFF(df * 16 + l16, kc * 4 + quad)]);
        acc[0][df] = MFMA16(pf0, vf, acc[0][df]);
        acc[1][df] = MFMA16(pf1, vf, acc[1][df]);
      }
    }
  };

  const int k0 = seg * 16;
  stage_kv(k0, Ks0, Vt0);          // prologue fill of buffer 0

#pragma unroll 1
  for (int i = 0; i < 8; i++) {
    __syncthreads();               // drains DMA->buf0 (issued a compute-phase ago)
    stage_kv(k0 + 2 * i + 1, Ks1, Vt1);     // prefetch next tile -> buf1
    compute_tile(Ks0, Vt0);
    __syncthreads();               // drains DMA->buf1; all waves done with buf0
    if (i < 7) stage_kv(k0 + 2 * i + 2, Ks0, Vt0);
    compute_tile(Ks1, Vt1);
  }

  // epilogue: store UNNORMALIZED partial (bf16) + l (fp32, lanes of quad 0)
#pragma unroll
  for (int qg = 0; qg < 2; qg++) {
    if (quad == 0)
      lpart[((size_t)(seg * 2 + b) * 6 + h) * 4096 + qt * 128 + w * 32 + qg * 16 + l16] = l_i[qg];
#pragma unroll
    for (int r = 0; r < 4; r++) {
      int row = qt * 128 + w * 32 + qg * 16 + quad * 4 + r;
      unsigned short* orow =
          Opart + (size_t)seg * 8192 * 768 + (size_t)(b * 4096 + row) * 768 + h * 128;
#pragma unroll
      for (int df = 0; df < 8; df++)
        orow[df * 16 + l16] = f2bf_fast(acc[qg][df][r]);
    }
  }
}

// ---------------- segment reduce: ob = (sum_s O_s) / (sum_s l_s) ----------------
__global__ __launch_bounds__(256) void k_reduce(const unsigned short* __restrict__ Opart,
                                                const float* __restrict__ lpart,
                                                unsigned short* __restrict__ ob) {
  int idx = (blockIdx.x * 256 + threadIdx.x) * 4;   // < 8192*768
  int row = idx / 768, col = idx - row * 768;
  int h = col >> 7;
  int b = row >> 12, r = row & 4095;

  float lt = 0.f;
#pragma unroll
  for (int s = 0; s < NSEG; s++)
    lt += lpart[((size_t)(s * 2 + b) * 6 + h) * 4096 + r];
  float inv = 1.0f / lt;

  float acc0 = 0.f, acc1 = 0.f, acc2 = 0.f, acc3 = 0.f;
#pragma unroll
  for (int s = 0; s < NSEG; s++) {
    ushort4v v = *(const ushort4v*)(&Opart[(size_t)s * 8192 * 768 + idx]);
    acc0 += bf2f(v.x);
    acc1 += bf2f(v.y);
    acc2 += bf2f(v.z);
    acc3 += bf2f(v.w);
  }
  ushort4v o;
  o.x = f2bf(acc0 * inv);
  o.y = f2bf(acc1 * inv);
  o.z = f2bf(acc2 * inv);
  o.w = f2bf(acc3 * inv);
  *(ushort4v*)(&ob[idx]) = o;
}

// ---------------- launch ----------------

extern "C" void kernel_launch(void* const* d_in, const int* in_sizes, int n_in,
                              void* d_out, int out_size, void* d_ws, size_t ws_size,
                              hipStream_t stream) {
  const float* x  = (const float*)d_in[0];
  const float* wq = (const float*)d_in[1];
  const float* wk = (const float*)d_in[2];
  const float* wv = (const float*)d_in[3];
  const float* wo = (const float*)d_in[4];
  float* out = (float*)d_out;

  char* ws = (char*)d_ws;
  unsigned short* xb    = (unsigned short*)(ws);                 // 12,582,912 B
  unsigned short* wqkvT = (unsigned short*)(ws + 12582912);      //  1,966,080 B
  unsigned short* woT   = (unsigned short*)(ws + 14548992);      //  1,179,648 B
  unsigned short* qkvb  = (unsigned short*)(ws + 15728640);      // 20,971,520 B
  unsigned short* ob    = (unsigned short*)(ws + 36700160);      // 12,582,912 B
  unsigned short* Opart = (unsigned short*)(ws + 49283072);      // 50,331,648 B (4 segs bf16)
  float*          lpart = (float*)(ws + 99614720);               //     786,432 B
  // vT (4 MB) aliases ob: written by QKV GEMM, read by k_attn (ob dead until
  // k_reduce, which runs after k_attn completes).
  unsigned short* vT    = ob;
  // total ws use: 100,401,152 B

  k_cvt_x<<<6144, 256, 0, stream>>>(x, xb, 8192 * 768);
  k_cvt_wqkv<<<3840, 256, 0, stream>>>(wq, wk, wv, wqkvT);
  k_cvt_wo<<<2304, 256, 0, stream>>>(wo, woT);

  // qkv = xb @ [wq|wk|wv]; V columns written transposed to vT
  k_gemm<unsigned short, true><<<dim3(10, 64), 256, 0, stream>>>(
      xb, 768, wqkvT, 768, qkvb, 1280, 768, vT);

  // attention: 4 KV-segments, unnormalized partials (128 q-rows/block)
  k_attn<<<dim3(32, 6, 2 * NSEG), 256, 0, stream>>>(qkvb, vT, Opart, lpart);

  // merge segments + normalize -> ob (overwrites vT region after k_attn)
  k_reduce<<<6144, 256, 0, stream>>>(Opart, lpart, ob);

  // out = ob @ wo           (M=8192, K=768, N=768), fp32 out
  k_gemm<float, false><<<dim3(6, 64), 256, 0, stream>>>(ob, 768, woT, 768, out, 768, 768, nullptr);
}

// Round 8
// 275.839 us; speedup vs baseline: 1.1862x; 1.1862x over previous
//
#include <hip/hip_runtime.h>

// ---------------------------------------------------------------------------
// BidirectionalAttention: B=2, S=4096, D=768, H=6, KVH=2, HD=128 (GQA x3)
// bf16 MFMA everywhere, fp32 accum.
// R8: k_attn LDS 80->48 KB (single-buffered K and V, staggered prefetch:
//     V(i) issued at top hides under S^T+softmax; K(i+1) issued mid hides
//     under PV). 48 KB -> 3 blocks/CU = 12 waves/CU = 3 waves/SIMD.
// ---------------------------------------------------------------------------

typedef __attribute__((ext_vector_type(8))) short bf16x8;   // 8 bf16 = 4 VGPRs
typedef __attribute__((ext_vector_type(4))) float floatx4;
typedef __attribute__((ext_vector_type(4))) unsigned short ushort4v;

#define MFMA16(a, b, c) __builtin_amdgcn_mfma_f32_16x16x32_bf16((a), (b), (c), 0, 0, 0)

#if __has_builtin(__builtin_amdgcn_exp2f)
#define EXP2F(x) __builtin_amdgcn_exp2f(x)
#else
#define EXP2F(x) exp2f(x)
#endif

#define GLOAD_LDS16(gptr, lptr)                                                   \
  __builtin_amdgcn_global_load_lds(                                               \
      (const __attribute__((address_space(1))) unsigned int*)(gptr),              \
      (__attribute__((address_space(3))) unsigned int*)(lptr), 16, 0, 0)

__device__ __forceinline__ unsigned short f2bf(float f) {   // RNE
  unsigned int u = __builtin_bit_cast(unsigned int, f);
  u = u + 0x7FFFu + ((u >> 16) & 1u);
  return (unsigned short)(u >> 16);
}

__device__ __forceinline__ unsigned short f2bf_fast(float f) {  // round-half-up
  unsigned int u = __builtin_bit_cast(unsigned int, f);
  return (unsigned short)((u + 0x8000u) >> 16);
}

__device__ __forceinline__ float bf2f(unsigned short v) {
  return __builtin_bit_cast(float, (unsigned int)v << 16);
}

// ---------------- convert kernels ----------------

__global__ __launch_bounds__(256) void k_cvt_x(const float* __restrict__ x,
                                               unsigned short* __restrict__ xb, int n) {
  int i = (blockIdx.x * 256 + threadIdx.x) * 4;
  if (i + 3 < n) {
    float4 v = *(const float4*)(x + i);
    xb[i + 0] = f2bf(v.x);
    xb[i + 1] = f2bf(v.y);
    xb[i + 2] = f2bf(v.z);
    xb[i + 3] = f2bf(v.w);
  }
}

__global__ __launch_bounds__(256) void k_cvt_wqkv(const float* __restrict__ wq,
                                                  const float* __restrict__ wk,
                                                  const float* __restrict__ wv,
                                                  unsigned short* __restrict__ wt) {
  const float QSCALE = 1.4426950408889634f * 0.08838834764831843f; // log2(e)/sqrt(128)
  int idx = blockIdx.x * 256 + threadIdx.x;       // < 1280*768
  int n = idx / 768, k = idx - n * 768;
  float v;
  if (n < 768)       v = wq[k * 768 + n] * QSCALE;
  else if (n < 1024) v = wk[k * 256 + (n - 768)];
  else               v = wv[k * 256 + (n - 1024)];
  wt[idx] = f2bf(v);
}

__global__ __launch_bounds__(256) void k_cvt_wo(const float* __restrict__ wo,
                                                unsigned short* __restrict__ wt) {
  int idx = blockIdx.x * 256 + threadIdx.x;       // < 768*768
  int n = idx / 768, k = idx - n * 768;
  wt[idx] = f2bf(wo[k * 768 + n]);
}

// ---------------- GEMM: C[M,N] = A[M,K] @ Bt[N,K]^T ----------------
// SPLIT_V: columns >=1024 (the V projection) are written TRANSPOSED to
// vTout[(b,kvh,d)][s] as packed 8B stores instead of to C.

__device__ __forceinline__ void store_out(float* C, int i, float v) { C[i] = v; }
__device__ __forceinline__ void store_out(unsigned short* C, int i, float v) { C[i] = f2bf(v); }

template <typename OUT_T, bool SPLIT_V>
__global__ __launch_bounds__(256) void k_gemm(const unsigned short* __restrict__ A, int lda,
                                              const unsigned short* __restrict__ Bt, int ldb,
                                              OUT_T* __restrict__ C, int ldc, int K,
                                              unsigned short* __restrict__ vTout) {
  __shared__ __align__(16) unsigned short As[128 * 40];
  __shared__ __align__(16) unsigned short Bs[128 * 40];
  const int tid = threadIdx.x;
  const int wave = tid >> 6, lane = tid & 63;
  const int quad = lane >> 4, l16 = lane & 15;
  const int wm = (wave >> 1) * 64, wn = (wave & 1) * 64;
  const int m0 = blockIdx.y * 128, n0 = blockIdx.x * 128;

  floatx4 acc[4][4] = {};
  const int srow = tid >> 2;
  const int sseg = (tid & 3) * 8;

  for (int k0 = 0; k0 < K; k0 += 32) {
    __syncthreads();
#pragma unroll
    for (int h = 0; h < 2; h++) {
      int r = srow + h * 64;
      *(uint4*)(&As[r * 40 + sseg]) = *(const uint4*)(&A[(m0 + r) * lda + k0 + sseg]);
      *(uint4*)(&Bs[r * 40 + sseg]) = *(const uint4*)(&Bt[(n0 + r) * ldb + k0 + sseg]);
    }
    __syncthreads();

    bf16x8 af[4], bfr[4];
#pragma unroll
    for (int mf = 0; mf < 4; mf++)
      af[mf] = *(const bf16x8*)(&As[(wm + mf * 16 + l16) * 40 + quad * 8]);
#pragma unroll
    for (int nf = 0; nf < 4; nf++)
      bfr[nf] = *(const bf16x8*)(&Bs[(wn + nf * 16 + l16) * 40 + quad * 8]);
#pragma unroll
    for (int mf = 0; mf < 4; mf++)
#pragma unroll
      for (int nf = 0; nf < 4; nf++)
        acc[mf][nf] = MFMA16(af[mf], bfr[nf], acc[mf][nf]);
  }

#pragma unroll
  for (int mf = 0; mf < 4; mf++)
#pragma unroll
    for (int nf = 0; nf < 4; nf++) {
      int col = n0 + wn + nf * 16 + l16;
      if (SPLIT_V && col >= 1024) {
        int cc = col - 1024;
        int kvhh = cc >> 7, d = cc & 127;
        int row0 = m0 + wm + mf * 16 + quad * 4;
        int bb = row0 >> 12, s = row0 & 4095;
        ushort4v pv;
        pv.x = f2bf(acc[mf][nf][0]);
        pv.y = f2bf(acc[mf][nf][1]);
        pv.z = f2bf(acc[mf][nf][2]);
        pv.w = f2bf(acc[mf][nf][3]);
        *(ushort4v*)(&vTout[((size_t)((bb * 2 + kvhh) * 128) + d) * 4096 + s]) = pv;
      } else {
#pragma unroll
        for (int r = 0; r < 4; r++) {
          int row = m0 + wm + mf * 16 + quad * 4 + r;
          store_out(C, row * ldc + col, acc[mf][nf][r]);
        }
      }
    }
}

// ---------------- flash attention (segmented, staggered single-buffer) -------
// grid (S/128, H, B*NSEG): z = seg*2 + b. 16 kt-iters per block, unnormalized
// O-partial (bf16) + l-partial (fp32). 256 thr = 4 waves; wave owns 32 q.
// Swizzled LDS (16B chunk c stored at c ^ (r&7)). LDS = 48 KB -> 3 blocks/CU.
// Pipeline per iter:
//   B1 (drains K(i)) | issue V(i)->Vt | S^T(i) on Ks | softmax->Ps
//   B2 (drains V(i); Ks free) | issue K(i+1)->Ks | PV(i) on Vt

#define NSEG 4

#define KS_OFF(row, c) (((row) << 7) + ((((c) ^ ((row) & 7))) << 3))
#define VS_OFF(row, c) (((row) << 6) + ((((c) ^ ((row) & 7))) << 3))

__global__ __launch_bounds__(256) void k_attn(const unsigned short* __restrict__ qkv,
                                              const unsigned short* __restrict__ vT,
                                              unsigned short* __restrict__ Opart,
                                              float* __restrict__ lpart) {
  __shared__ __align__(16) unsigned short Ks[64 * 128];   // 16 KB (K tile / Q rows 0-63)
  __shared__ __align__(16) unsigned short Vt[128 * 64];   // 16 KB (V^T tile / Q rows 64-127)
  __shared__ __align__(16) unsigned short Ps[128 * 64];   // 16 KB

  const int qt = blockIdx.x, h = blockIdx.y;
  const int seg = blockIdx.z >> 1, b = blockIdx.z & 1;
  const int kvh = h / 3;
  const int tid = threadIdx.x, w = tid >> 6, lane = tid & 63;
  const int quad = lane >> 4, l16 = lane & 15;

  const char* qbase = (const char*)(qkv + (size_t)(b * 4096) * 1280 + h * 128);
  const char* kbase = (const char*)(qkv + (size_t)(b * 4096) * 1280 + 768 + kvh * 128);
  const char* vtb   = (const char*)(vT + (size_t)((b * 2 + kvh) * 128) * 4096);

  bf16x8 qf[2][4];
  floatx4 acc[2][8] = {};
  float l_i[2] = {0.f, 0.f};

  // ---- stage Q tile (128x128): rows 0-63 -> Ks, rows 64-127 -> Vt ----
#pragma unroll
  for (int it = 0; it < 8; it++) {
    int cb = it * 256 + w * 64;              // wave-uniform chunk base
    int j = cb + lane;
    int r = j >> 4, c = (j & 15) ^ (r & 7);
    unsigned short* dst = (cb < 1024) ? &Ks[cb * 8] : &Vt[(cb - 1024) * 8];
    GLOAD_LDS16(qbase + (size_t)(qt * 128 + r) * 2560 + c * 16, dst);
  }
  __syncthreads();

  // wave w owns q-rows w*32..w*32+31; rows 0-63 in Ks, 64-127 in Vt
  {
    const unsigned short* qsrc = (w < 2) ? Ks : Vt;
    const int qr0 = (w & 1) * 32;
#pragma unroll
    for (int qg = 0; qg < 2; qg++)
#pragma unroll
      for (int dc = 0; dc < 4; dc++)
        qf[qg][dc] = *(const bf16x8*)(&qsrc[KS_OFF(qr0 + qg * 16 + l16, dc * 4 + quad)]);
  }
  __syncthreads();   // all waves done reading Q

  auto stage_k = [&](int kt) {
#pragma unroll
    for (int it = 0; it < 4; it++) {
      int cb = it * 256 + w * 64;
      int j = cb + lane;
      int r = j >> 4, c = (j & 15) ^ (r & 7);
      GLOAD_LDS16(kbase + (size_t)(kt * 64 + r) * 2560 + c * 16, &Ks[cb * 8]);
    }
  };
  auto stage_v = [&](int kt) {
#pragma unroll
    for (int it = 0; it < 4; it++) {
      int cb = it * 256 + w * 64;
      int j = cb + lane;
      int r = j >> 3, c = (j & 7) ^ (r & 7);
      GLOAD_LDS16(vtb + (size_t)r * 8192 + kt * 128 + c * 16, &Vt[cb * 8]);
    }
  };

  const int k0 = seg * 16;
  stage_k(k0);   // prologue

#pragma unroll 1
  for (int i = 0; i < 16; i++) {
    __syncthreads();             // B1: drains K(i); Vt free (PV(i-1) done by all)
    stage_v(k0 + i);             // V(i) hides under S^T + softmax

    // S^T = K Q^T : D[m=kcol][n=q]; kf reused across both q-groups
    floatx4 sfr[2][4] = {};
#pragma unroll
    for (int nf = 0; nf < 4; nf++)
#pragma unroll
      for (int dc = 0; dc < 4; dc++) {
        bf16x8 kf = *(const bf16x8*)(&Ks[KS_OFF(nf * 16 + l16, dc * 4 + quad)]);
        sfr[0][nf] = MFMA16(kf, qf[0][dc], sfr[0][nf]);
        sfr[1][nf] = MFMA16(kf, qf[1][dc], sfr[1][nf]);
      }

    // no-max softmax; P -> wave-private swizzled LDS rows (b64 packed)
#pragma unroll
    for (int qg = 0; qg < 2; qg++) {
      float rs = 0.f;
#pragma unroll
      for (int nf = 0; nf < 4; nf++) {
#pragma unroll
        for (int r = 0; r < 4; r++) {
          float p = EXP2F(sfr[qg][nf][r]);
          sfr[qg][nf][r] = p;
          rs += p;
        }
        int row = w * 32 + qg * 16 + l16;
        int ch = nf * 2 + (quad >> 1);
        ushort4v pw;
        pw.x = f2bf_fast(sfr[qg][nf][0]);
        pw.y = f2bf_fast(sfr[qg][nf][1]);
        pw.z = f2bf_fast(sfr[qg][nf][2]);
        pw.w = f2bf_fast(sfr[qg][nf][3]);
        *(ushort4v*)(&Ps[VS_OFF(row, ch) + (quad & 1) * 4]) = pw;
      }
      rs += __shfl_xor(rs, 16, 64);
      rs += __shfl_xor(rs, 32, 64);
      l_i[qg] += rs;
    }

    __syncthreads();             // B2: drains V(i); all waves done S^T(i) -> Ks free
    if (i < 15) stage_k(k0 + i + 1);   // K(i+1) hides under PV

    // O += P V : vf reused across both q-groups (wave-private P: DS in-order)
#pragma unroll
    for (int kc = 0; kc < 2; kc++) {
      bf16x8 pf0 = *(const bf16x8*)(&Ps[VS_OFF(w * 32 + l16, kc * 4 + quad)]);
      bf16x8 pf1 = *(const bf16x8*)(&Ps[VS_OFF(w * 32 + 16 + l16, kc * 4 + quad)]);
#pragma unroll
      for (int df = 0; df < 8; df++) {
        bf16x8 vf = *(const bf16x8*)(&Vt[VS_OFF(df * 16 + l16, kc * 4 + quad)]);
        acc[0][df] = MFMA16(pf0, vf, acc[0][df]);
        acc[1][df] = MFMA16(pf1, vf, acc[1][df]);
      }
    }
  }

  // epilogue: store UNNORMALIZED partial (bf16) + l (fp32, lanes of quad 0)
#pragma unroll
  for (int qg = 0; qg < 2; qg++) {
    if (quad == 0)
      lpart[((size_t)(seg * 2 + b) * 6 + h) * 4096 + qt * 128 + w * 32 + qg * 16 + l16] = l_i[qg];
#pragma unroll
    for (int r = 0; r < 4; r++) {
      int row = qt * 128 + w * 32 + qg * 16 + quad * 4 + r;
      unsigned short* orow =
          Opart + (size_t)seg * 8192 * 768 + (size_t)(b * 4096 + row) * 768 + h * 128;
#pragma unroll
      for (int df = 0; df < 8; df++)
        orow[df * 16 + l16] = f2bf_fast(acc[qg][df][r]);
    }
  }
}

// ---------------- segment reduce: ob = (sum_s O_s) / (sum_s l_s) ----------------
__global__ __launch_bounds__(256) void k_reduce(const unsigned short* __restrict__ Opart,
                                                const float* __restrict__ lpart,
                                                unsigned short* __restrict__ ob) {
  int idx = (blockIdx.x * 256 + threadIdx.x) * 4;   // < 8192*768
  int row = idx / 768, col = idx - row * 768;
  int h = col >> 7;
  int b = row >> 12, r = row & 4095;

  float lt = 0.f;
#pragma unroll
  for (int s = 0; s < NSEG; s++)
    lt += lpart[((size_t)(s * 2 + b) * 6 + h) * 4096 + r];
  float inv = 1.0f / lt;

  float acc0 = 0.f, acc1 = 0.f, acc2 = 0.f, acc3 = 0.f;
#pragma unroll
  for (int s = 0; s < NSEG; s++) {
    ushort4v v = *(const ushort4v*)(&Opart[(size_t)s * 8192 * 768 + idx]);
    acc0 += bf2f(v.x);
    acc1 += bf2f(v.y);
    acc2 += bf2f(v.z);
    acc3 += bf2f(v.w);
  }
  ushort4v o;
  o.x = f2bf(acc0 * inv);
  o.y = f2bf(acc1 * inv);
  o.z = f2bf(acc2 * inv);
  o.w = f2bf(acc3 * inv);
  *(ushort4v*)(&ob[idx]) = o;
}

// ---------------- launch ----------------

extern "C" void kernel_launch(void* const* d_in, const int* in_sizes, int n_in,
                              void* d_out, int out_size, void* d_ws, size_t ws_size,
                              hipStream_t stream) {
  const float* x  = (const float*)d_in[0];
  const float* wq = (const float*)d_in[1];
  const float* wk = (const float*)d_in[2];
  const float* wv = (const float*)d_in[3];
  const float* wo = (const float*)d_in[4];
  float* out = (float*)d_out;

  char* ws = (char*)d_ws;
  unsigned short* xb    = (unsigned short*)(ws);                 // 12,582,912 B
  unsigned short* wqkvT = (unsigned short*)(ws + 12582912);      //  1,966,080 B
  unsigned short* woT   = (unsigned short*)(ws + 14548992);      //  1,179,648 B
  unsigned short* qkvb  = (unsigned short*)(ws + 15728640);      // 20,971,520 B
  unsigned short* ob    = (unsigned short*)(ws + 36700160);      // 12,582,912 B
  unsigned short* Opart = (unsigned short*)(ws + 49283072);      // 50,331,648 B (4 segs bf16)
  float*          lpart = (float*)(ws + 99614720);               //     786,432 B
  // vT (4 MB) aliases ob: written by QKV GEMM, read by k_attn (ob dead until
  // k_reduce, which runs after k_attn completes).
  unsigned short* vT    = ob;
  // total ws use: 100,401,152 B

  k_cvt_x<<<6144, 256, 0, stream>>>(x, xb, 8192 * 768);
  k_cvt_wqkv<<<3840, 256, 0, stream>>>(wq, wk, wv, wqkvT);
  k_cvt_wo<<<2304, 256, 0, stream>>>(wo, woT);

  // qkv = xb @ [wq|wk|wv]; V columns written transposed to vT
  k_gemm<unsigned short, true><<<dim3(10, 64), 256, 0, stream>>>(
      xb, 768, wqkvT, 768, qkvb, 1280, 768, vT);

  // attention: 4 KV-segments, unnormalized partials (128 q-rows/block)
  k_attn<<<dim3(32, 6, 2 * NSEG), 256, 0, stream>>>(qkvb, vT, Opart, lpart);

  // merge segments + normalize -> ob (overwrites vT region after k_attn)
  k_reduce<<<6144, 256, 0, stream>>>(Opart, lpart, ob);

  // out = ob @ wo           (M=8192, K=768, N=768), fp32 out
  k_gemm<float, false><<<dim3(6, 64), 256, 0, stream>>>(ob, 768, woT, 768, out, 768, 768, nullptr);
}

// Round 9
// 255.573 us; speedup vs baseline: 1.2803x; 1.0793x over previous
//
#include <hip/hip_runtime.h>

// ---------------------------------------------------------------------------
// BidirectionalAttention: B=2, S=4096, D=768, H=6, KVH=2, HD=128 (GQA x3)
// bf16 MFMA everywhere, fp32 accum.
// R9: k_gemm upgraded to global_load_lds width-16 staging + double-buffered
//     prefetch (R6 trick); weight converts collapsed into one LDS-tiled
//     coalesced transpose kernel. k_attn unchanged from R8.
// ---------------------------------------------------------------------------

typedef __attribute__((ext_vector_type(8))) short bf16x8;   // 8 bf16 = 4 VGPRs
typedef __attribute__((ext_vector_type(4))) float floatx4;
typedef __attribute__((ext_vector_type(4))) unsigned short ushort4v;

#define MFMA16(a, b, c) __builtin_amdgcn_mfma_f32_16x16x32_bf16((a), (b), (c), 0, 0, 0)

#if __has_builtin(__builtin_amdgcn_exp2f)
#define EXP2F(x) __builtin_amdgcn_exp2f(x)
#else
#define EXP2F(x) exp2f(x)
#endif

#define GLOAD_LDS16(gptr, lptr)                                                   \
  __builtin_amdgcn_global_load_lds(                                               \
      (const __attribute__((address_space(1))) unsigned int*)(gptr),              \
      (__attribute__((address_space(3))) unsigned int*)(lptr), 16, 0, 0)

__device__ __forceinline__ unsigned short f2bf(float f) {   // RNE
  unsigned int u = __builtin_bit_cast(unsigned int, f);
  u = u + 0x7FFFu + ((u >> 16) & 1u);
  return (unsigned short)(u >> 16);
}

__device__ __forceinline__ unsigned short f2bf_fast(float f) {  // round-half-up
  unsigned int u = __builtin_bit_cast(unsigned int, f);
  return (unsigned short)((u + 0x8000u) >> 16);
}

__device__ __forceinline__ float bf2f(unsigned short v) {
  return __builtin_bit_cast(float, (unsigned int)v << 16);
}

// ---------------- convert kernels ----------------

__global__ __launch_bounds__(256) void k_cvt_x(const float* __restrict__ x,
                                               unsigned short* __restrict__ xb, int n) {
  int i = (blockIdx.x * 256 + threadIdx.x) * 4;
  if (i + 3 < n) {
    float4 v = *(const float4*)(x + i);
    xb[i + 0] = f2bf(v.x);
    xb[i + 1] = f2bf(v.y);
    xb[i + 2] = f2bf(v.z);
    xb[i + 3] = f2bf(v.w);
  }
}

// Tiled transpose+convert for all weights. grid (12 kb, 32 nb), 256 thr.
// nb 0-11: wq -> wqkvT rows 0-767 (scaled); 12-15: wk -> rows 768-1023;
// 16-19: wv -> rows 1024-1279; 20-31: wo -> woT rows 0-767.
__global__ __launch_bounds__(256) void k_cvt_w(const float* __restrict__ wq,
                                               const float* __restrict__ wk,
                                               const float* __restrict__ wv,
                                               const float* __restrict__ wo,
                                               unsigned short* __restrict__ wqkvT,
                                               unsigned short* __restrict__ woT) {
  __shared__ float T[64 * 65];
  const float QSCALE = 1.4426950408889634f * 0.08838834764831843f; // log2(e)/sqrt(128)
  const int kb = blockIdx.x, nb = blockIdx.y, tid = threadIdx.x;

  const float* src; int ld, col0; unsigned short* dst; int n0; float scale = 1.0f;
  if (nb < 12)      { src = wq; ld = 768; col0 = nb * 64;        dst = wqkvT; n0 = nb * 64; scale = QSCALE; }
  else if (nb < 16) { src = wk; ld = 256; col0 = (nb - 12) * 64; dst = wqkvT; n0 = nb * 64; }
  else if (nb < 20) { src = wv; ld = 256; col0 = (nb - 16) * 64; dst = wqkvT; n0 = nb * 64; }
  else              { src = wo; ld = 768; col0 = (nb - 20) * 64; dst = woT;   n0 = (nb - 20) * 64; }

  const int k0 = kb * 64;
  {
    int cc = tid & 63, kk0 = tid >> 6;
#pragma unroll
    for (int it = 0; it < 16; it++) {
      int kk = kk0 + it * 4;
      T[kk * 65 + cc] = src[(size_t)(k0 + kk) * ld + col0 + cc] * scale;
    }
  }
  __syncthreads();
  {
    int kk = tid & 63, nn0 = tid >> 6;
#pragma unroll
    for (int it = 0; it < 16; it++) {
      int nn = nn0 + it * 4;
      dst[(size_t)(n0 + nn) * 768 + k0 + kk] = f2bf(T[kk * 65 + nn]);
    }
  }
}

// ---------------- GEMM: C[M,N] = A[M,K] @ Bt[N,K]^T ----------------
// 128x128 tile, BK=32, double-buffered global_load_lds staging (16B DMA,
// chunk swizzle c' = c ^ (r&3) folded into the global source address).
// SPLIT_V: columns >=1024 (V projection) written TRANSPOSED to vTout.

__device__ __forceinline__ void store_out(float* C, int i, float v) { C[i] = v; }
__device__ __forceinline__ void store_out(unsigned short* C, int i, float v) { C[i] = f2bf(v); }

template <typename OUT_T, bool SPLIT_V>
__global__ __launch_bounds__(256) void k_gemm(const unsigned short* __restrict__ A, int lda,
                                              const unsigned short* __restrict__ Bt, int ldb,
                                              OUT_T* __restrict__ C, int ldc, int K,
                                              unsigned short* __restrict__ vTout) {
  __shared__ __align__(16) unsigned short As0[128 * 32];   // 8 KB each
  __shared__ __align__(16) unsigned short As1[128 * 32];
  __shared__ __align__(16) unsigned short Bs0[128 * 32];
  __shared__ __align__(16) unsigned short Bs1[128 * 32];

  const int tid = threadIdx.x;
  const int wave = tid >> 6, lane = tid & 63;
  const int quad = lane >> 4, l16 = lane & 15;
  const int wm = (wave >> 1) * 64, wn = (wave & 1) * 64;
  const int m0 = blockIdx.y * 128, n0 = blockIdx.x * 128;

  floatx4 acc[4][4] = {};

  // stage one 128x32 slice: 512 16B-chunks, 2 per thread; chunk j holds
  // row r = j>>2, col-chunk c = (j&3) ^ (r&3) (swizzle via source address)
  auto stage = [&](const unsigned short* G, int ld, int row0, int k0, unsigned short* S) {
#pragma unroll
    for (int it = 0; it < 2; it++) {
      int j = it * 256 + tid;
      int r = j >> 2, c = (j & 3) ^ (r & 3);
      GLOAD_LDS16((const char*)(G + (size_t)(row0 + r) * ld + k0 + c * 8), &S[j * 8]);
    }
  };

  const int xq = (quad ^ (l16 & 3)) * 8;   // swizzled chunk offset for frags
  auto compute = [&](const unsigned short* As, const unsigned short* Bs) {
    bf16x8 af[4], bfr[4];
#pragma unroll
    for (int mf = 0; mf < 4; mf++)
      af[mf] = *(const bf16x8*)(&As[(wm + mf * 16 + l16) * 32 + xq]);
#pragma unroll
    for (int nf = 0; nf < 4; nf++)
      bfr[nf] = *(const bf16x8*)(&Bs[(wn + nf * 16 + l16) * 32 + xq]);
#pragma unroll
    for (int mf = 0; mf < 4; mf++)
#pragma unroll
      for (int nf = 0; nf < 4; nf++)
        acc[mf][nf] = MFMA16(af[mf], bfr[nf], acc[mf][nf]);
  };

  stage(A, lda, m0, 0, As0);
  stage(Bt, ldb, n0, 0, Bs0);

  const int half = K >> 6;   // K/64 ping-pong pairs (K multiple of 64)
#pragma unroll 1
  for (int i = 0; i < half; i++) {
    __syncthreads();                       // drains DMA -> buf0
    stage(A, lda, m0, (2 * i + 1) * 32, As1);
    stage(Bt, ldb, n0, (2 * i + 1) * 32, Bs1);
    compute(As0, Bs0);
    __syncthreads();                       // drains DMA -> buf1
    if (i < half - 1) {
      stage(A, lda, m0, (2 * i + 2) * 32, As0);
      stage(Bt, ldb, n0, (2 * i + 2) * 32, Bs0);
    }
    compute(As1, Bs1);
  }

#pragma unroll
  for (int mf = 0; mf < 4; mf++)
#pragma unroll
    for (int nf = 0; nf < 4; nf++) {
      int col = n0 + wn + nf * 16 + l16;
      if (SPLIT_V && col >= 1024) {
        int cc = col - 1024;
        int kvhh = cc >> 7, d = cc & 127;
        int row0 = m0 + wm + mf * 16 + quad * 4;
        int bb = row0 >> 12, s = row0 & 4095;
        ushort4v pv;
        pv.x = f2bf(acc[mf][nf][0]);
        pv.y = f2bf(acc[mf][nf][1]);
        pv.z = f2bf(acc[mf][nf][2]);
        pv.w = f2bf(acc[mf][nf][3]);
        *(ushort4v*)(&vTout[((size_t)((bb * 2 + kvhh) * 128) + d) * 4096 + s]) = pv;
      } else {
#pragma unroll
        for (int r = 0; r < 4; r++) {
          int row = m0 + wm + mf * 16 + quad * 4 + r;
          store_out(C, row * ldc + col, acc[mf][nf][r]);
        }
      }
    }
}

// ---------------- flash attention (segmented, staggered single-buffer) -------
// (unchanged from R8) grid (S/128, H, B*NSEG); 256 thr = 4 waves; 48 KB LDS.

#define NSEG 4

#define KS_OFF(row, c) (((row) << 7) + ((((c) ^ ((row) & 7))) << 3))
#define VS_OFF(row, c) (((row) << 6) + ((((c) ^ ((row) & 7))) << 3))

__global__ __launch_bounds__(256) void k_attn(const unsigned short* __restrict__ qkv,
                                              const unsigned short* __restrict__ vT,
                                              unsigned short* __restrict__ Opart,
                                              float* __restrict__ lpart) {
  __shared__ __align__(16) unsigned short Ks[64 * 128];   // 16 KB
  __shared__ __align__(16) unsigned short Vt[128 * 64];   // 16 KB
  __shared__ __align__(16) unsigned short Ps[128 * 64];   // 16 KB

  const int qt = blockIdx.x, h = blockIdx.y;
  const int seg = blockIdx.z >> 1, b = blockIdx.z & 1;
  const int kvh = h / 3;
  const int tid = threadIdx.x, w = tid >> 6, lane = tid & 63;
  const int quad = lane >> 4, l16 = lane & 15;

  const char* qbase = (const char*)(qkv + (size_t)(b * 4096) * 1280 + h * 128);
  const char* kbase = (const char*)(qkv + (size_t)(b * 4096) * 1280 + 768 + kvh * 128);
  const char* vtb   = (const char*)(vT + (size_t)((b * 2 + kvh) * 128) * 4096);

  bf16x8 qf[2][4];
  floatx4 acc[2][8] = {};
  float l_i[2] = {0.f, 0.f};

  // stage Q tile (128x128): rows 0-63 -> Ks, rows 64-127 -> Vt
#pragma unroll
  for (int it = 0; it < 8; it++) {
    int cb = it * 256 + w * 64;
    int j = cb + lane;
    int r = j >> 4, c = (j & 15) ^ (r & 7);
    unsigned short* dst = (cb < 1024) ? &Ks[cb * 8] : &Vt[(cb - 1024) * 8];
    GLOAD_LDS16(qbase + (size_t)(qt * 128 + r) * 2560 + c * 16, dst);
  }
  __syncthreads();

  {
    const unsigned short* qsrc = (w < 2) ? Ks : Vt;
    const int qr0 = (w & 1) * 32;
#pragma unroll
    for (int qg = 0; qg < 2; qg++)
#pragma unroll
      for (int dc = 0; dc < 4; dc++)
        qf[qg][dc] = *(const bf16x8*)(&qsrc[KS_OFF(qr0 + qg * 16 + l16, dc * 4 + quad)]);
  }
  __syncthreads();

  auto stage_k = [&](int kt) {
#pragma unroll
    for (int it = 0; it < 4; it++) {
      int cb = it * 256 + w * 64;
      int j = cb + lane;
      int r = j >> 4, c = (j & 15) ^ (r & 7);
      GLOAD_LDS16(kbase + (size_t)(kt * 64 + r) * 2560 + c * 16, &Ks[cb * 8]);
    }
  };
  auto stage_v = [&](int kt) {
#pragma unroll
    for (int it = 0; it < 4; it++) {
      int cb = it * 256 + w * 64;
      int j = cb + lane;
      int r = j >> 3, c = (j & 7) ^ (r & 7);
      GLOAD_LDS16(vtb + (size_t)r * 8192 + kt * 128 + c * 16, &Vt[cb * 8]);
    }
  };

  const int k0 = seg * 16;
  stage_k(k0);

#pragma unroll 1
  for (int i = 0; i < 16; i++) {
    __syncthreads();             // B1: drains K(i); Vt free
    stage_v(k0 + i);             // V(i) hides under S^T + softmax

    floatx4 sfr[2][4] = {};
#pragma unroll
    for (int nf = 0; nf < 4; nf++)
#pragma unroll
      for (int dc = 0; dc < 4; dc++) {
        bf16x8 kf = *(const bf16x8*)(&Ks[KS_OFF(nf * 16 + l16, dc * 4 + quad)]);
        sfr[0][nf] = MFMA16(kf, qf[0][dc], sfr[0][nf]);
        sfr[1][nf] = MFMA16(kf, qf[1][dc], sfr[1][nf]);
      }

#pragma unroll
    for (int qg = 0; qg < 2; qg++) {
      float rs = 0.f;
#pragma unroll
      for (int nf = 0; nf < 4; nf++) {
#pragma unroll
        for (int r = 0; r < 4; r++) {
          float p = EXP2F(sfr[qg][nf][r]);
          sfr[qg][nf][r] = p;
          rs += p;
        }
        int row = w * 32 + qg * 16 + l16;
        int ch = nf * 2 + (quad >> 1);
        ushort4v pw;
        pw.x = f2bf_fast(sfr[qg][nf][0]);
        pw.y = f2bf_fast(sfr[qg][nf][1]);
        pw.z = f2bf_fast(sfr[qg][nf][2]);
        pw.w = f2bf_fast(sfr[qg][nf][3]);
        *(ushort4v*)(&Ps[VS_OFF(row, ch) + (quad & 1) * 4]) = pw;
      }
      rs += __shfl_xor(rs, 16, 64);
      rs += __shfl_xor(rs, 32, 64);
      l_i[qg] += rs;
    }

    __syncthreads();             // B2: drains V(i); Ks free
    if (i < 15) stage_k(k0 + i + 1);   // K(i+1) hides under PV

#pragma unroll
    for (int kc = 0; kc < 2; kc++) {
      bf16x8 pf0 = *(const bf16x8*)(&Ps[VS_OFF(w * 32 + l16, kc * 4 + quad)]);
      bf16x8 pf1 = *(const bf16x8*)(&Ps[VS_OFF(w * 32 + 16 + l16, kc * 4 + quad)]);
#pragma unroll
      for (int df = 0; df < 8; df++) {
        bf16x8 vf = *(const bf16x8*)(&Vt[VS_OFF(df * 16 + l16, kc * 4 + quad)]);
        acc[0][df] = MFMA16(pf0, vf, acc[0][df]);
        acc[1][df] = MFMA16(pf1, vf, acc[1][df]);
      }
    }
  }

  // epilogue: UNNORMALIZED partial (bf16) + l (fp32)
#pragma unroll
  for (int qg = 0; qg < 2; qg++) {
    if (quad == 0)
      lpart[((size_t)(seg * 2 + b) * 6 + h) * 4096 + qt * 128 + w * 32 + qg * 16 + l16] = l_i[qg];
#pragma unroll
    for (int r = 0; r < 4; r++) {
      int row = qt * 128 + w * 32 + qg * 16 + quad * 4 + r;
      unsigned short* orow =
          Opart + (size_t)seg * 8192 * 768 + (size_t)(b * 4096 + row) * 768 + h * 128;
#pragma unroll
      for (int df = 0; df < 8; df++)
        orow[df * 16 + l16] = f2bf_fast(acc[qg][df][r]);
    }
  }
}

// ---------------- segment reduce: ob = (sum_s O_s) / (sum_s l_s) ----------------
__global__ __launch_bounds__(256) void k_reduce(const unsigned short* __restrict__ Opart,
                                                const float* __restrict__ lpart,
                                                unsigned short* __restrict__ ob) {
  int idx = (blockIdx.x * 256 + threadIdx.x) * 4;   // < 8192*768
  int row = idx / 768, col = idx - row * 768;
  int h = col >> 7;
  int b = row >> 12, r = row & 4095;

  float lt = 0.f;
#pragma unroll
  for (int s = 0; s < NSEG; s++)
    lt += lpart[((size_t)(s * 2 + b) * 6 + h) * 4096 + r];
  float inv = 1.0f / lt;

  float acc0 = 0.f, acc1 = 0.f, acc2 = 0.f, acc3 = 0.f;
#pragma unroll
  for (int s = 0; s < NSEG; s++) {
    ushort4v v = *(const ushort4v*)(&Opart[(size_t)s * 8192 * 768 + idx]);
    acc0 += bf2f(v.x);
    acc1 += bf2f(v.y);
    acc2 += bf2f(v.z);
    acc3 += bf2f(v.w);
  }
  ushort4v o;
  o.x = f2bf(acc0 * inv);
  o.y = f2bf(acc1 * inv);
  o.z = f2bf(acc2 * inv);
  o.w = f2bf(acc3 * inv);
  *(ushort4v*)(&ob[idx]) = o;
}

// ---------------- launch ----------------

extern "C" void kernel_launch(void* const* d_in, const int* in_sizes, int n_in,
                              void* d_out, int out_size, void* d_ws, size_t ws_size,
                              hipStream_t stream) {
  const float* x  = (const float*)d_in[0];
  const float* wq = (const float*)d_in[1];
  const float* wk = (const float*)d_in[2];
  const float* wv = (const float*)d_in[3];
  const float* wo = (const float*)d_in[4];
  float* out = (float*)d_out;

  char* ws = (char*)d_ws;
  unsigned short* xb    = (unsigned short*)(ws);                 // 12,582,912 B
  unsigned short* wqkvT = (unsigned short*)(ws + 12582912);      //  1,966,080 B
  unsigned short* woT   = (unsigned short*)(ws + 14548992);      //  1,179,648 B
  unsigned short* qkvb  = (unsigned short*)(ws + 15728640);      // 20,971,520 B
  unsigned short* ob    = (unsigned short*)(ws + 36700160);      // 12,582,912 B
  unsigned short* Opart = (unsigned short*)(ws + 49283072);      // 50,331,648 B
  float*          lpart = (float*)(ws + 99614720);               //     786,432 B
  unsigned short* vT    = ob;   // alias: ob dead until k_reduce; vT dead after k_attn
  // total ws use: 100,401,152 B

  k_cvt_x<<<6144, 256, 0, stream>>>(x, xb, 8192 * 768);
  k_cvt_w<<<dim3(12, 32), 256, 0, stream>>>(wq, wk, wv, wo, wqkvT, woT);

  // qkv = xb @ [wq|wk|wv]; V columns written transposed to vT
  k_gemm<unsigned short, true><<<dim3(10, 64), 256, 0, stream>>>(
      xb, 768, wqkvT, 768, qkvb, 1280, 768, vT);

  // attention: 4 KV-segments, unnormalized partials (128 q-rows/block)
  k_attn<<<dim3(32, 6, 2 * NSEG), 256, 0, stream>>>(qkvb, vT, Opart, lpart);

  // merge segments + normalize -> ob (overwrites vT region after k_attn)
  k_reduce<<<6144, 256, 0, stream>>>(Opart, lpart, ob);

  // out = ob @ wo           (M=8192, K=768, N=768), fp32 out
  k_gemm<float, false><<<dim3(6, 64), 256, 0, stream>>>(ob, 768, woT, 768, out, 768, 768, nullptr);
}